// Round 1
// baseline (556.665 us; speedup 1.0000x reference)
//
#include <hip/hip_runtime.h>

typedef __attribute__((ext_vector_type(8))) short  short8;
typedef __attribute__((ext_vector_type(4))) short  short4v;
typedef __attribute__((ext_vector_type(4))) float  f32x4;
typedef __attribute__((ext_vector_type(8))) __bf16 bf8_t;

#define DMODEL 1024
#define SEQ    2048
#define NB     4
#define NH     16
#define MTOT   (NB * SEQ)

static __device__ __forceinline__ ushort f2bf(float f) {
  union { float f; unsigned u; } v; v.f = f;
  unsigned r = v.u + 0x7fffu + ((v.u >> 16) & 1u);
  return (ushort)(r >> 16);
}

static __device__ __forceinline__ f32x4 mfma32(short8 a, short8 b, f32x4 c) {
  return __builtin_amdgcn_mfma_f32_16x16x32_bf16(
      __builtin_bit_cast(bf8_t, a), __builtin_bit_cast(bf8_t, b), c, 0, 0, 0);
}

static __device__ __forceinline__ f32x4 mfma16(short4v a, short4v b, f32x4 c) {
#if __has_builtin(__builtin_amdgcn_mfma_f32_16x16x16bf16_1k)
  return __builtin_amdgcn_mfma_f32_16x16x16bf16_1k(a, b, c, 0, 0, 0);
#else
  asm volatile("v_mfma_f32_16x16x16_bf16 %0, %1, %2, %0" : "+v"(c) : "v"(a), "v"(b));
  return c;
#endif
}

// ---------------- weight transpose: W (K x N) fp32 -> Wt (N x K) bf16 ----------
__global__ __launch_bounds__(1024) void wtrans_k(
    const float* __restrict__ Wq, const float* __restrict__ Wk,
    const float* __restrict__ Wv, const float* __restrict__ Wo,
    ushort* __restrict__ Wt) {
  __shared__ float tile[32][33];
  const int z = blockIdx.z;
  const float* W = (z == 0) ? Wq : (z == 1) ? Wk : (z == 2) ? Wv : Wo;
  ushort* out = Wt + (size_t)z * DMODEL * DMODEL;
  const int tx = threadIdx.x, ty = threadIdx.y;
  const int n0 = blockIdx.x * 32, k0 = blockIdx.y * 32;
  tile[ty][tx] = W[(size_t)(k0 + ty) * DMODEL + n0 + tx];
  __syncthreads();
  out[(size_t)(n0 + ty) * DMODEL + k0 + tx] = f2bf(tile[tx][ty]);
}

// ---------------- GEMM: C = A(fp32, MxK) * W + bias ---------------------------
// Bt is N x K row-major bf16 (pre-transposed). MODE 0: write bf16 permuted to
// (b,h,s,dk). MODE 1: write fp32 row-major.
template <int MODE>
__global__ __launch_bounds__(256) void gemm_k(
    const float* __restrict__ A, const ushort* __restrict__ Bt,
    const float* __restrict__ bias, void* __restrict__ out) {
  __shared__ ushort Alds[128][40];
  __shared__ ushort Blds[128][40];
  const int tid = threadIdx.x;
  const int wid = tid >> 6, lane = tid & 63;
  const int wr = wid >> 1, wc = wid & 1;
  const int lr = lane & 15, lg = lane >> 4;
  const int m0 = blockIdx.x * 128, n0 = blockIdx.y * 128;
  const int arow = tid >> 1, ahalf = tid & 1;

  f32x4 acc[4][4];
#pragma unroll
  for (int m = 0; m < 4; m++)
#pragma unroll
    for (int n = 0; n < 4; n++) acc[m][n] = (f32x4){0.f, 0.f, 0.f, 0.f};

  for (int k0 = 0; k0 < DMODEL; k0 += 32) {
    // stage A: fp32 -> bf16 into LDS (each thread 16 elements)
    const float4* ap =
        (const float4*)(A + (size_t)(m0 + arow) * DMODEL + k0 + ahalf * 16);
    float4 a0 = ap[0], a1 = ap[1], a2 = ap[2], a3 = ap[3];
    short8 s01, s23;
    s01[0] = (short)f2bf(a0.x); s01[1] = (short)f2bf(a0.y);
    s01[2] = (short)f2bf(a0.z); s01[3] = (short)f2bf(a0.w);
    s01[4] = (short)f2bf(a1.x); s01[5] = (short)f2bf(a1.y);
    s01[6] = (short)f2bf(a1.z); s01[7] = (short)f2bf(a1.w);
    s23[0] = (short)f2bf(a2.x); s23[1] = (short)f2bf(a2.y);
    s23[2] = (short)f2bf(a2.z); s23[3] = (short)f2bf(a2.w);
    s23[4] = (short)f2bf(a3.x); s23[5] = (short)f2bf(a3.y);
    s23[6] = (short)f2bf(a3.z); s23[7] = (short)f2bf(a3.w);
    *(short8*)&Alds[arow][ahalf * 16]     = s01;
    *(short8*)&Alds[arow][ahalf * 16 + 8] = s23;
    // stage B (already bf16)
    const short8* bp =
        (const short8*)(Bt + (size_t)(n0 + arow) * DMODEL + k0 + ahalf * 16);
    short8 b01 = bp[0], b23 = bp[1];
    *(short8*)&Blds[arow][ahalf * 16]     = b01;
    *(short8*)&Blds[arow][ahalf * 16 + 8] = b23;
    __syncthreads();

    short8 af[4], bfr[4];
#pragma unroll
    for (int m = 0; m < 4; m++)
      af[m] = *(const short8*)&Alds[wr * 64 + m * 16 + lr][lg * 8];
#pragma unroll
    for (int n = 0; n < 4; n++)
      bfr[n] = *(const short8*)&Blds[wc * 64 + n * 16 + lr][lg * 8];
#pragma unroll
    for (int m = 0; m < 4; m++)
#pragma unroll
      for (int n = 0; n < 4; n++) acc[m][n] = mfma32(af[m], bfr[n], acc[m][n]);
    __syncthreads();
  }

  float bv4[4];
#pragma unroll
  for (int n = 0; n < 4; n++) bv4[n] = bias[n0 + wc * 64 + n * 16 + lr];
#pragma unroll
  for (int m = 0; m < 4; m++) {
    const int grb = m0 + wr * 64 + m * 16 + lg * 4;
#pragma unroll
    for (int n = 0; n < 4; n++) {
      const int gc = n0 + wc * 64 + n * 16 + lr;
#pragma unroll
      for (int j = 0; j < 4; j++) {
        float val = acc[m][n][j] + bv4[n];
        int r = grb + j;
        if (MODE == 0) {
          int b = r >> 11, s = r & 2047, hh = gc >> 6, dk = gc & 63;
          ((ushort*)out)[((((size_t)b * NH + hh) * SEQ) + s) * 64 + dk] =
              f2bf(val);
        } else {
          ((float*)out)[(size_t)r * DMODEL + gc] = val;
        }
      }
    }
  }
}

// ---------------- flash attention ---------------------------------------------
// grid (SEQ/64, NB*NH), block 256. Wave w handles 16 q rows. Swapped QK^T:
// sT = mfma(K, Q) -> C[key][q], softmax per lane (q = lane&15), P^T feeds PV
// B-operand directly; O^T accumulated via mfma(V^T, P^T).
__global__ __launch_bounds__(256) void attn_k(
    const ushort* __restrict__ Qp, const ushort* __restrict__ Kp,
    const ushort* __restrict__ Vp, const int* __restrict__ mask,
    float* __restrict__ ctx) {
  const int tid = threadIdx.x, w = tid >> 6, lane = tid & 63;
  const int lr = lane & 15, lg = lane >> 4;
  const int bh = blockIdx.y, b = bh >> 4, h = bh & 15;
  const int q0 = blockIdx.x * 64 + w * 16;
  const ushort* Qh = Qp + (size_t)bh * SEQ * 64;
  const ushort* Kh = Kp + (size_t)bh * SEQ * 64;
  const ushort* Vh = Vp + (size_t)bh * SEQ * 64;
  const int* mb = mask + b * SEQ;

  const short8 qf0 = *(const short8*)&Qh[(size_t)(q0 + lr) * 64 + lg * 8];
  const short8 qf1 = *(const short8*)&Qh[(size_t)(q0 + lr) * 64 + 32 + lg * 8];

  float m_run = -1e30f, l_run = 0.f;
  f32x4 accO[4];
#pragma unroll
  for (int t = 0; t < 4; t++) accO[t] = (f32x4){0.f, 0.f, 0.f, 0.f};
  const float scale = 0.125f;  // 1/sqrt(64)

  for (int kb = 0; kb < SEQ; kb += 16) {
    const short8 kf0 = *(const short8*)&Kh[(size_t)(kb + lr) * 64 + lg * 8];
    const short8 kf1 = *(const short8*)&Kh[(size_t)(kb + lr) * 64 + 32 + lg * 8];
    f32x4 st = (f32x4){0.f, 0.f, 0.f, 0.f};
    st = mfma32(kf0, qf0, st);
    st = mfma32(kf1, qf1, st);

    float s[4];
#pragma unroll
    for (int j = 0; j < 4; j++) {
      s[j] = st[j] * scale;
      int key = kb + lg * 4 + j;
      if (mb[key] == 0) s[j] = -1e30f;
    }
    float tmax = fmaxf(fmaxf(s[0], s[1]), fmaxf(s[2], s[3]));
    tmax = fmaxf(tmax, __shfl_xor(tmax, 16));
    tmax = fmaxf(tmax, __shfl_xor(tmax, 32));
    const float m_new = fmaxf(m_run, tmax);
    const float alpha = __expf(m_run - m_new);
    float p[4], psum = 0.f;
#pragma unroll
    for (int j = 0; j < 4; j++) {
      p[j] = __expf(s[j] - m_new);
      psum += p[j];
    }
    psum += __shfl_xor(psum, 16);
    psum += __shfl_xor(psum, 32);
    l_run = l_run * alpha + psum;
    m_run = m_new;
#pragma unroll
    for (int t = 0; t < 4; t++)
#pragma unroll
      for (int j = 0; j < 4; j++) accO[t][j] *= alpha;

    short4v pt;
#pragma unroll
    for (int j = 0; j < 4; j++) pt[j] = (short)f2bf(p[j]);

#pragma unroll
    for (int t = 0; t < 4; t++) {
      short4v vf;
#pragma unroll
      for (int i = 0; i < 4; i++)
        vf[i] = (short)Vh[(size_t)(kb + lg * 4 + i) * 64 + t * 16 + lr];
      accO[t] = mfma16(vf, pt, accO[t]);
    }
  }

  const float inv = 1.f / l_run;
  const size_t base = ((size_t)b * SEQ + q0 + lr) * DMODEL + h * 64;
#pragma unroll
  for (int t = 0; t < 4; t++)
#pragma unroll
    for (int j = 0; j < 4; j++)
      ctx[base + t * 16 + lg * 4 + j] = accO[t][j] * inv;
}

// ---------------- host ---------------------------------------------------------
extern "C" void kernel_launch(void* const* d_in, const int* in_sizes, int n_in,
                              void* d_out, int out_size, void* d_ws,
                              size_t ws_size, hipStream_t stream) {
  const float* q    = (const float*)d_in[0];
  const float* k    = (const float*)d_in[1];
  const float* v    = (const float*)d_in[2];
  const int*   mask = (const int*)d_in[3];
  const float* Wq   = (const float*)d_in[4];
  const float* bq   = (const float*)d_in[5];
  const float* Wk   = (const float*)d_in[6];
  const float* bk   = (const float*)d_in[7];
  const float* Wv   = (const float*)d_in[8];
  const float* bv   = (const float*)d_in[9];
  const float* Wo   = (const float*)d_in[10];
  const float* bo   = (const float*)d_in[11];

  char* p = (char*)d_ws;
  ushort* Wt = (ushort*)p; p += (size_t)4 * DMODEL * DMODEL * 2;
  ushort* Qp = (ushort*)p; p += (size_t)MTOT * DMODEL * 2;
  ushort* Kp = (ushort*)p; p += (size_t)MTOT * DMODEL * 2;
  ushort* Vp = (ushort*)p; p += (size_t)MTOT * DMODEL * 2;
  float*  ctx = (float*)p;

  wtrans_k<<<dim3(32, 32, 4), dim3(32, 32), 0, stream>>>(Wq, Wk, Wv, Wo, Wt);

  dim3 gg(MTOT / 128, DMODEL / 128);
  gemm_k<0><<<gg, 256, 0, stream>>>(q, Wt, bq, Qp);
  gemm_k<0><<<gg, 256, 0, stream>>>(k, Wt + (size_t)DMODEL * DMODEL, bk, Kp);
  gemm_k<0><<<gg, 256, 0, stream>>>(v, Wt + (size_t)2 * DMODEL * DMODEL, bv, Vp);

  attn_k<<<dim3(SEQ / 64, NB * NH), 256, 0, stream>>>(Qp, Kp, Vp, mask, ctx);

  gemm_k<1><<<gg, 256, 0, stream>>>(ctx, Wt + (size_t)3 * DMODEL * DMODEL, bo,
                                    d_out);
}